// Round 1
// baseline (209.664 us; speedup 1.0000x reference)
//
#include <hip/hip_runtime.h>
#include <hip/hip_bf16.h>

// ALiBi attention, B=8 L=1024 H=8 E=64, fp32 in/out, bf16 MFMA inside.
// Outputs: V [B,L,H,E] then series [B,H,L,L], concatenated in d_out.

typedef short short8 __attribute__((ext_vector_type(8)));
typedef float f32x4 __attribute__((ext_vector_type(4)));
typedef unsigned short u16x4 __attribute__((ext_vector_type(4)));

#define B_ 8
#define L_ 1024
#define H_ 8
#define E_ 64
#define QBLK 16
#define KVBLK 128
#define SPAD 1032  // 1024 + 8 pad: b128 frag reads land 2-way max
#define KPAD 72    // 64 + 8 pad
#define VPAD 136   // 128 + 8 pad

__device__ __forceinline__ unsigned short f2bf(float f) {
  return __builtin_bit_cast(unsigned short, __float2bfloat16(f));
}

__global__ __launch_bounds__(256, 2) void alibi_attn(
    const float* __restrict__ Qg, const float* __restrict__ Kg,
    const float* __restrict__ Vg, float* __restrict__ Vout,
    float* __restrict__ Pout) {
  __shared__ unsigned short sS[QBLK][SPAD];     // scores, then P (bf16 bits)
  __shared__ unsigned short sQ[QBLK][KPAD];     // Q tile bf16
  __shared__ unsigned short sKV[KVBLK * KPAD];  // union: K chunk [128][72] / VT [64][136]

  const int t = threadIdx.x;
  const int lane = t & 63;
  const int w = t >> 6;        // wave 0..3
  const int q0 = blockIdx.x * QBLK;
  const int h = blockIdx.y;
  const int b = blockIdx.z;
  const int col = lane & 15;   // M/N index inside a 16x16 tile
  const int kg = lane >> 4;    // k-group 0..3

  const float scale = 0.125f;                         // 1/sqrt(64)
  const float slope = exp2f(-(float)(h + 1) * 0.125f); // 2^-((h+1)/8)

  // ---- stage Q tile: 16x64 fp32 -> bf16, one float4 per thread ----
  {
    const int r = t >> 4, e = (t & 15) * 4;
    float4 v = *reinterpret_cast<const float4*>(
        &Qg[(((size_t)b * L_ + q0 + r) * H_ + h) * E_ + e]);
    *reinterpret_cast<u16x4*>(&sQ[r][e]) =
        (u16x4){f2bf(v.x), f2bf(v.y), f2bf(v.z), f2bf(v.w)};
  }
  __syncthreads();

  // ---- Phase 1: S = scale*Q.K^T + alibi, bf16 into sS ----
  for (int c = 0; c < L_ / KVBLK; ++c) {
    const int kv0 = c * KVBLK;
    {
      const int e = (t & 15) * 4;
#pragma unroll
      for (int ss = 0; ss < KVBLK; ss += 16) {
        const int s = ss + (t >> 4);
        float4 v = *reinterpret_cast<const float4*>(
            &Kg[(((size_t)b * L_ + kv0 + s) * H_ + h) * E_ + e]);
        *reinterpret_cast<u16x4*>(&sKV[s * KPAD + e]) =
            (u16x4){f2bf(v.x), f2bf(v.y), f2bf(v.z), f2bf(v.w)};
      }
    }
    __syncthreads();
#pragma unroll
    for (int kt = 0; kt < 2; ++kt) {
      const int keyloc = 32 * w + 16 * kt;  // this wave's 16-key tile in chunk
      f32x4 acc = {0.f, 0.f, 0.f, 0.f};
#pragma unroll
      for (int ks = 0; ks < 2; ++ks) {
        short8 a = *reinterpret_cast<const short8*>(&sQ[col][ks * 32 + kg * 8]);
        short8 bb = *reinterpret_cast<const short8*>(
            &sKV[(keyloc + col) * KPAD + ks * 32 + kg * 8]);
        acc = __builtin_amdgcn_mfma_f32_16x16x32_bf16(a, bb, acc, 0, 0, 0);
      }
      const int key = kv0 + keyloc + col;  // global key index (D col)
      const float bias = slope * (float)(key - (L_ - 1));
#pragma unroll
      for (int r = 0; r < 4; ++r) {
        sS[kg * 4 + r][key] = f2bf(acc[r] * scale + bias);
      }
    }
    __syncthreads();
  }

  // ---- Phase 2: row softmax, write series, overwrite sS with bf16 P ----
  {
    float* PoutBH = Pout + (((size_t)b * H_ + h) * L_ + q0) * L_;
#pragma unroll
    for (int rr = 0; rr < 4; ++rr) {
      const int r = w + 4 * rr;  // wave w owns rows w, w+4, w+8, w+12
      float vals[16];
#pragma unroll
      for (int i = 0; i < 8; ++i) {
        unsigned int u =
            *reinterpret_cast<const unsigned int*>(&sS[r][2 * lane + 128 * i]);
        vals[2 * i] = __uint_as_float(u << 16);
        vals[2 * i + 1] = __uint_as_float(u & 0xffff0000u);
      }
      float m = -3.0e38f;
#pragma unroll
      for (int i = 0; i < 16; ++i) m = fmaxf(m, vals[i]);
#pragma unroll
      for (int off = 32; off >= 1; off >>= 1)
        m = fmaxf(m, __shfl_xor(m, off, 64));
      float zs = 0.f;
#pragma unroll
      for (int i = 0; i < 16; ++i) {
        vals[i] = exp2f((vals[i] - m) * 1.44269504f);
        zs += vals[i];
      }
#pragma unroll
      for (int off = 32; off >= 1; off >>= 1) zs += __shfl_xor(zs, off, 64);
      const float inv = 1.0f / zs;
#pragma unroll
      for (int i = 0; i < 8; ++i) {
        const int cc = 2 * lane + 128 * i;
        const float p0 = vals[2 * i] * inv, p1 = vals[2 * i + 1] * inv;
        *reinterpret_cast<float2*>(&PoutBH[(size_t)r * L_ + cc]) =
            make_float2(p0, p1);
        *reinterpret_cast<unsigned int*>(&sS[r][cc]) =
            ((unsigned int)f2bf(p1) << 16) | (unsigned int)f2bf(p0);
      }
    }
  }
  __syncthreads();

  // ---- Phase 3: O = P.V via MFMA; V staged transposed (VT[e][s]) ----
  f32x4 oacc = {0.f, 0.f, 0.f, 0.f};
  for (int c = 0; c < L_ / KVBLK; ++c) {
    const int kv0 = c * KVBLK;
    {
      const int e = (t & 15) * 4;
#pragma unroll
      for (int ss = 0; ss < KVBLK; ss += 16) {
        const int s = ss + (t >> 4);
        float4 v = *reinterpret_cast<const float4*>(
            &Vg[(((size_t)b * L_ + kv0 + s) * H_ + h) * E_ + e]);
        sKV[(e + 0) * VPAD + s] = f2bf(v.x);
        sKV[(e + 1) * VPAD + s] = f2bf(v.y);
        sKV[(e + 2) * VPAD + s] = f2bf(v.z);
        sKV[(e + 3) * VPAD + s] = f2bf(v.w);
      }
    }
    __syncthreads();
#pragma unroll
    for (int ks = 0; ks < 4; ++ks) {
      short8 a = *reinterpret_cast<const short8*>(
          &sS[col][kv0 + ks * 32 + kg * 8]);
      short8 bb = *reinterpret_cast<const short8*>(
          &sKV[(16 * w + col) * VPAD + ks * 32 + kg * 8]);
      oacc = __builtin_amdgcn_mfma_f32_16x16x32_bf16(a, bb, oacc, 0, 0, 0);
    }
    __syncthreads();
  }
  {
    const int e = 16 * w + col;
#pragma unroll
    for (int r = 0; r < 4; ++r) {
      Vout[(((size_t)b * L_ + q0 + kg * 4 + r) * H_ + h) * E_ + e] = oacc[r];
    }
  }
}

extern "C" void kernel_launch(void* const* d_in, const int* in_sizes, int n_in,
                              void* d_out, int out_size, void* d_ws,
                              size_t ws_size, hipStream_t stream) {
  const float* Q = (const float*)d_in[0];
  const float* K = (const float*)d_in[1];
  const float* V = (const float*)d_in[2];
  float* out = (float*)d_out;
  float* Vout = out;                                   // [B,L,H,E]
  float* Pout = out + (size_t)B_ * L_ * H_ * E_;       // [B,H,L,L]
  dim3 grid(L_ / QBLK, H_, B_);
  hipLaunchKernelGGL(alibi_attn, grid, dim3(256), 0, stream, Q, K, V, Vout,
                     Pout);
}

// Round 2
// 189.556 us; speedup vs baseline: 1.1061x; 1.1061x over previous
//
#include <hip/hip_runtime.h>
#include <hip/hip_bf16.h>

// ALiBi attention, B=8 L=1024 H=8 E=64, fp32 in/out, bf16 MFMA inside.
// Outputs: V [B,L,H,E] then series [B,H,L,L], concatenated in d_out.
// Two-pass online softmax: pass A = stats only (m, Z in registers),
// pass B = recompute S, write P from D-frag, PV via MFMA.

typedef short short8 __attribute__((ext_vector_type(8)));
typedef float f32x4 __attribute__((ext_vector_type(4)));
typedef unsigned short u16x4 __attribute__((ext_vector_type(4)));

#define B_ 8
#define L_ 1024
#define H_ 8
#define E_ 64
#define QBLK 64    // 4 waves x 16 rows
#define CHUNK 128  // keys per chunk
#define KPAD 72    // K tile row stride (ushorts), 16B-aligned rows
#define VPAD 136   // VT tile row stride (ushorts), 16B-aligned rows

__device__ __forceinline__ unsigned short f2bf(float f) {
  return __builtin_bit_cast(unsigned short, __float2bfloat16(f));
}

__global__ __launch_bounds__(256, 3) void alibi_attn(
    const float* __restrict__ Qg, const float* __restrict__ Kg,
    const float* __restrict__ Vg, float* __restrict__ Vout,
    float* __restrict__ Pout) {
  __shared__ unsigned short sK[CHUNK * KPAD];   // K chunk [128][72]
  __shared__ unsigned short sVT[E_ * VPAD];     // V^T chunk [64][136], XOR-swz
  __shared__ unsigned short sP[4][16 * 128];    // per-wave P tile, XOR-swz

  const int t = threadIdx.x;
  const int lane = t & 63;
  const int w = t >> 6;       // wave 0..3, owns q rows 16w..16w+15
  const int col = lane & 15;
  const int kg = lane >> 4;
  const int q0 = blockIdx.x * QBLK;
  const int h = blockIdx.y;
  const int b = blockIdx.z;

  const float L2E = 1.44269504f;
  const float sc_l2e = 0.125f * L2E;  // scale * log2e
  const float sl_l2e = exp2f(-(float)(h + 1) * 0.125f) * L2E;

  // ---- Q fragments (A-frag): row = lane&15, k = 8*kg + j (+32*ks) ----
  short8 qf[2];
  {
    const float* qp =
        &Qg[(((size_t)b * L_ + q0 + 16 * w + col) * H_ + h) * E_ + 8 * kg];
#pragma unroll
    for (int ks = 0; ks < 2; ++ks) {
      float4 a0 = *reinterpret_cast<const float4*>(qp + 32 * ks);
      float4 a1 = *reinterpret_cast<const float4*>(qp + 32 * ks + 4);
      qf[ks] = (short8){(short)f2bf(a0.x), (short)f2bf(a0.y), (short)f2bf(a0.z),
                        (short)f2bf(a0.w), (short)f2bf(a1.x), (short)f2bf(a1.y),
                        (short)f2bf(a1.z), (short)f2bf(a1.w)};
    }
  }

  float m_[4], z_[4];
#pragma unroll
  for (int r = 0; r < 4; ++r) {
    m_[r] = -3.0e38f;
    z_[r] = 0.f;
  }

  // ======== Pass A: online (m, Z) ========
  for (int c = 0; c < L_ / CHUNK; ++c) {
    const int kv0 = c * CHUNK;
    {  // stage K chunk -> sK (coalesced float4, b64 LDS writes)
      const int e = 4 * (t & 15);
#pragma unroll
      for (int it = 0; it < 8; ++it) {
        const int s = (t >> 4) + 16 * it;
        float4 v = *reinterpret_cast<const float4*>(
            &Kg[(((size_t)b * L_ + kv0 + s) * H_ + h) * E_ + e]);
        *reinterpret_cast<u16x4*>(&sK[s * KPAD + e]) =
            (u16x4){f2bf(v.x), f2bf(v.y), f2bf(v.z), f2bf(v.w)};
      }
    }
    __syncthreads();
#pragma unroll
    for (int kt = 0; kt < 8; ++kt) {
      f32x4 acc = {0.f, 0.f, 0.f, 0.f};
#pragma unroll
      for (int ks = 0; ks < 2; ++ks) {
        short8 kf = *reinterpret_cast<const short8*>(
            &sK[(16 * kt + col) * KPAD + 32 * ks + 8 * kg]);
        acc = __builtin_amdgcn_mfma_f32_16x16x32_bf16(qf[ks], kf, acc, 0, 0, 0);
      }
      const float vb = sl_l2e * (float)(kv0 + 16 * kt + col - (L_ - 1));
#pragma unroll
      for (int r = 0; r < 4; ++r) {
        float u = acc[r] * sc_l2e + vb;
        float mo = m_[r];
        float mn = fmaxf(mo, u);
        z_[r] = z_[r] * exp2f(mo - mn) + exp2f(u - mn);
        m_[r] = mn;
      }
    }
    __syncthreads();
  }

  // combine (m,z) across the 16 lanes sharing each row
  float mfin_[4], minv_[4];
#pragma unroll
  for (int r = 0; r < 4; ++r) {
    float m = m_[r], z = z_[r];
#pragma unroll
    for (int off = 1; off < 16; off <<= 1) {
      float m2 = __shfl_xor(m, off, 64);
      float z2 = __shfl_xor(z, off, 64);
      float mn = fmaxf(m, m2);
      z = z * exp2f(m - mn) + z2 * exp2f(m2 - mn);
      m = mn;
    }
    mfin_[r] = m;
    minv_[r] = 1.0f / z;
  }

  // ======== Pass B: recompute S, write P, accumulate PV ========
  f32x4 oacc[4];
#pragma unroll
  for (int et = 0; et < 4; ++et) oacc[et] = (f32x4){0.f, 0.f, 0.f, 0.f};

  float* Pb = Pout + ((size_t)(b * H_ + h) * L_ + q0 + 16 * w) * L_;
  unsigned short* sPw = &sP[w][0];

  for (int c = 0; c < L_ / CHUNK; ++c) {
    const int kv0 = c * CHUNK;
    {  // stage K chunk
      const int e = 4 * (t & 15);
#pragma unroll
      for (int it = 0; it < 8; ++it) {
        const int s = (t >> 4) + 16 * it;
        float4 v = *reinterpret_cast<const float4*>(
            &Kg[(((size_t)b * L_ + kv0 + s) * H_ + h) * E_ + e]);
        *reinterpret_cast<u16x4*>(&sK[s * KPAD + e]) =
            (u16x4){f2bf(v.x), f2bf(v.y), f2bf(v.z), f2bf(v.w)};
      }
    }
    {  // stage V^T chunk: thread reads 4 s for one e (wave-coalesced per load)
      const int e = t & 63;
      const int swz = 16 * (e >> 3);
#pragma unroll
      for (int i = 0; i < 8; ++i) {
        const int s4 = 4 * (t >> 6) + 16 * i;
        const float* vp = &Vg[(((size_t)b * L_ + kv0 + s4) * H_ + h) * E_ + e];
        float x0 = vp[0 * H_ * E_], x1 = vp[1 * H_ * E_];
        float x2 = vp[2 * H_ * E_], x3 = vp[3 * H_ * E_];
        *reinterpret_cast<u16x4*>(&sVT[e * VPAD + (s4 ^ swz)]) =
            (u16x4){f2bf(x0), f2bf(x1), f2bf(x2), f2bf(x3)};
      }
    }
    __syncthreads();

    // recompute S tile-by-tile, emit P (global fp32 + LDS bf16)
#pragma unroll
    for (int kt = 0; kt < 8; ++kt) {
      f32x4 acc = {0.f, 0.f, 0.f, 0.f};
#pragma unroll
      for (int ks = 0; ks < 2; ++ks) {
        short8 kf = *reinterpret_cast<const short8*>(
            &sK[(16 * kt + col) * KPAD + 32 * ks + 8 * kg]);
        acc = __builtin_amdgcn_mfma_f32_16x16x32_bf16(qf[ks], kf, acc, 0, 0, 0);
      }
      const int kv = kv0 + 16 * kt + col;
      const float vb = sl_l2e * (float)(kv - (L_ - 1));
#pragma unroll
      for (int r = 0; r < 4; ++r) {
        float u = acc[r] * sc_l2e + vb;
        float pf = exp2f(u - mfin_[r]) * minv_[r];
        const int row = 4 * kg + r;
        __builtin_nontemporal_store(pf, &Pb[row * L_ + kv]);
        sPw[row * 128 + ((16 * kt + col) ^ (row << 3))] = f2bf(pf);
      }
    }

    // PV: O += P(chunk) * V(chunk)   (sP is wave-private; no barrier needed)
#pragma unroll
    for (int ks = 0; ks < 4; ++ks) {
      short8 af = *reinterpret_cast<const short8*>(
          &sPw[col * 128 + ((32 * ks + 8 * kg) ^ (col << 3))]);
#pragma unroll
      for (int et = 0; et < 4; ++et) {
        const int erow = 16 * et + col;
        short8 vf = *reinterpret_cast<const short8*>(
            &sVT[erow * VPAD + ((32 * ks + 8 * kg) ^ (16 * (erow >> 3)))]);
        oacc[et] = __builtin_amdgcn_mfma_f32_16x16x32_bf16(af, vf, oacc[et], 0, 0, 0);
      }
    }
    __syncthreads();
  }

  // ---- write O ----
  float* Vb = Vout + (((size_t)b * L_ + q0 + 16 * w) * H_ + h) * E_;
#pragma unroll
  for (int et = 0; et < 4; ++et) {
#pragma unroll
    for (int r = 0; r < 4; ++r) {
      __builtin_nontemporal_store(oacc[et][r],
                                  &Vb[(4 * kg + r) * H_ * E_ + 16 * et + col]);
    }
  }
}

extern "C" void kernel_launch(void* const* d_in, const int* in_sizes, int n_in,
                              void* d_out, int out_size, void* d_ws,
                              size_t ws_size, hipStream_t stream) {
  const float* Q = (const float*)d_in[0];
  const float* K = (const float*)d_in[1];
  const float* V = (const float*)d_in[2];
  float* out = (float*)d_out;
  float* Vo = out;                              // [B,L,H,E]
  float* Po = out + (size_t)B_ * L_ * H_ * E_;  // [B,H,L,L]
  dim3 grid(L_ / QBLK, H_, B_);
  hipLaunchKernelGGL(alibi_attn, grid, dim3(256), 0, stream, Q, K, V, Vo, Po);
}